// Round 5
// baseline (244.955 us; speedup 1.0000x reference)
//
#include <hip/hip_runtime.h>
#include <hip/hip_bf16.h>

typedef __attribute__((ext_vector_type(8))) short bf16x8;
typedef __attribute__((ext_vector_type(4))) float f32x4;
typedef __attribute__((ext_vector_type(2))) float f32x2;

struct Params {
  const float* x[6];
  const float* W[6];
  const float* cg;
  float* out;
};

constexpr int NPAIRS_C[6] = {6, 15, 21, 24, 24, 21};
constexpr int POFF_C[6]   = {0, 6, 21, 42, 66, 90};
constexpr int KL_C[6]   = {3456, 8640, 12096, 13824, 13824, 12096};
constexpr int LOFF_C[6] = {0, 1, 4, 9, 16, 25};   // row offset of l in xall

constexpr int TL1[111] = {
  0,1,2,3,4,5,
  0,1,1,1,2,2,2,3,3,3,4,4,4,5,5,
  0,1,1,1,2,2,2,2,2,3,3,3,3,3,4,4,4,4,5,5,5,
  0,1,1,1,2,2,2,2,2,3,3,3,3,3,3,4,4,4,4,4,5,5,5,5,
  0,1,1,1,2,2,2,2,3,3,3,3,3,4,4,4,4,4,4,5,5,5,5,5,
  0,1,1,2,2,2,3,3,3,3,4,4,4,4,4,5,5,5,5,5,5
};
constexpr int TL2R[111] = {
  0,1,2,3,4,5,
  1,0,1,2,1,2,3,2,3,4,3,4,5,4,5,
  2,1,2,3,0,1,2,3,4,1,2,3,4,5,2,3,4,5,3,4,5,
  3,2,3,4,1,2,3,4,5,0,1,2,3,4,5,1,2,3,4,5,2,3,4,5,
  4,3,4,5,2,3,4,5,1,2,3,4,5,0,1,2,3,4,5,1,2,3,4,5,
  5,4,5,3,4,5,2,3,4,5,1,2,3,4,5,0,1,2,3,4,5
};

__constant__ int c_l1[111] = {
  0,1,2,3,4,5,
  0,1,1,1,2,2,2,3,3,3,4,4,4,5,5,
  0,1,1,1,2,2,2,2,2,3,3,3,3,3,4,4,4,4,5,5,5,
  0,1,1,1,2,2,2,2,2,3,3,3,3,3,3,4,4,4,4,4,5,5,5,5,
  0,1,1,1,2,2,2,2,3,3,3,3,3,4,4,4,4,4,4,5,5,5,5,5,
  0,1,1,2,2,2,3,3,3,3,4,4,4,4,4,5,5,5,5,5,5
};
__constant__ int c_l2[111] = {
  0,1,2,3,4,5,
  1,0,1,2,1,2,3,2,3,4,3,4,5,4,5,
  2,1,2,3,0,1,2,3,4,1,2,3,4,5,2,3,4,5,3,4,5,
  3,2,3,4,1,2,3,4,5,0,1,2,3,4,5,1,2,3,4,5,2,3,4,5,
  4,3,4,5,2,3,4,5,1,2,3,4,5,0,1,2,3,4,5,1,2,3,4,5,
  5,4,5,3,4,5,2,3,4,5,1,2,3,4,5,0,1,2,3,4,5
};
// 21 (L, mp0) blocks, heavy-L first; each block covers mp0, mp0+1
__constant__ int c_mb_l[21]  = {5,5,5,5,5,5, 4,4,4,4,4, 3,3,3,3, 2,2,2, 1,1, 0};
__constant__ int c_mb_m0[21] = {0,2,4,6,8,10, 0,2,4,6,8, 0,2,4,6, 0,2,4, 0,2, 0};
// chunk-pair groups: group g = chunks (GA[g], GA[g]+3) — same d0, c differs by 4
__constant__ int c_GA[9] = {0,1,2,6,7,8,12,13,14};

// ---------- LDS layout (float units) ----------
// xall: [36 rows][stride 196] f32 (row = LOFF[l]+i, col = b*24+c, b<8)
#define XALL_F 0
#define CG_F   7056       // [2][NP][12] f32 <= 576
#define RED_F  7632       // [9][16][32] f32 = 4608
#define SMEM_FLOATS 12240 // 48,960 B -> 3 blocks/CU

__device__ __forceinline__ bf16x8 cvt8(f32x4 lo, f32x4 hi) {
  union { unsigned int u[4]; bf16x8 v; } z;
  union { __hip_bfloat162 h2; unsigned int u; } y;
  y.h2 = __float22bfloat162_rn(make_float2(lo.x, lo.y)); z.u[0] = y.u;
  y.h2 = __float22bfloat162_rn(make_float2(lo.z, lo.w)); z.u[1] = y.u;
  y.h2 = __float22bfloat162_rn(make_float2(hi.x, hi.y)); z.u[2] = y.u;
  y.h2 = __float22bfloat162_rn(make_float2(hi.z, hi.w)); z.u[3] = y.u;
  return z.v;
}

template<int L>
__device__ __forceinline__ void body(const Params& P, const int mp0, const int btile) {
  constexpr int NP  = NPAIRS_C[L];
  constexpr int OFF = POFF_C[L];
  constexpr int KL  = KL_C[L];
  extern __shared__ float smem[];
  float* xall  = smem + XALL_F;
  float* cgall = smem + CG_F;
  float* red   = smem + RED_F;

  const int t    = threadIdx.x;          // 576 threads = 9 waves
  const int lane = t & 63;
  const int w    = t >> 6;               // wave = group id (0..8)
  const int q8   = lane >> 4;            // A-frag k-quad
  const int rI   = lane & 15;            // A-frag row: b = rI&7, mpL = rI>>3
  const int b    = rI & 7;
  const int mpL  = rI >> 3;
  const int b0   = btile * 8;

  // ---- stage all x, transposed, fp32 ----
#pragma unroll
  for (int l = 0; l < 6; ++l) {
    const int n = 2 * l + 1;
    const float* src = P.x[l] + (size_t)b0 * 24 * n;
    const int tot = 8 * 24 * n;
    for (int e = t; e < tot; e += 576) {
      const int bc = e / n;                  // compile-time divisor
      const int i  = e - bc * n;
      xall[(LOFF_C[l] + i) * 196 + bc] = src[e];
    }
  }
  // ---- stage cg diagonals for mp0 and mp0+1 (zeros where invalid) ----
  for (int e = t; e < 2 * NP * 12; e += 576) {
    const int i  = e % 12;
    const int r  = e / 12;
    const int pi = r % NP;
    const int mL = r / NP;
    const int l1 = c_l1[OFF + pi], l2 = c_l2[OFF + pi];
    const int mp = mp0 + mL;
    const int j  = mp + l1 + l2 - L - i;
    float v = 0.f;
    if (mp <= 2 * L && i <= 2 * l1 && j >= 0 && j <= 2 * l2)
      v = P.cg[((size_t)(((l1 * 6 + l2) * 6 + L) * 11 + mp) * 11 + i) * 11 + j];
    cgall[(mL * NP + pi) * 12 + i] = v;
  }
  __syncthreads();

  f32x4 accC0 = {0.f, 0.f, 0.f, 0.f};   // h 0..15
  f32x4 accC1 = {0.f, 0.f, 0.f, 0.f};   // h 16..31
  const int colb = b * 24;

  // this wave's single chunk-pair group
  const int kcA = c_GA[w];
  const int k0  = kcA * 32 + q8 * 8;
  const int cA  = k0 / 24;               // div by constant -> magic mul
  const int d0  = k0 - cA * 24;          // in {0,8,16}
  const float* x2base = xall + colb + d0;
  const float* x1base = xall + colb + cA;   // x1 for B-chunk at +4 (c = cA+4)

  // W row bases for on-the-fly B-fragments (fp32, L2-resident)
  const float* rowA = P.W[L] + (size_t)(lane & 15) * KL + k0;      // h = lane&15
  const float* rowB = rowA + (size_t)16 * KL;                      // h = 16 + (lane&15)

#pragma unroll
  for (int pi = 0; pi < NP; ++pi) {
    const int l1 = TL1[OFF + pi], l2 = TL2R[OFF + pi];   // folded by unroll
    const int n1 = 2 * l1 + 1, n2 = 2 * l2 + 1;
    const int R1 = LOFF_C[l1], R2 = LOFF_C[l2];
    const int mK0w = mp0 + l1 + l2 - L;        // wave-uniform (mpL=0)
    const int mK0l = mK0w + mpL;               // per-lane
    const int i0 = (mK0w - (n2 - 1)) > 0 ? (mK0w - (n2 - 1)) : 0;
    const int i1 = (n1 - 1) < (mK0w + 1) ? (n1 - 1) : (mK0w + 1);

    // prefetch W fp32 (8x f32x4); latency hides under the diag loop
    const float* wpA = rowA + pi * 576;
    const float* wpB = rowB + pi * 576;
    const f32x4 wA0lo = *(const f32x4*)(wpA);
    const f32x4 wA0hi = *(const f32x4*)(wpA + 4);
    const f32x4 wA1lo = *(const f32x4*)(wpB);
    const f32x4 wA1hi = *(const f32x4*)(wpB + 4);
    const f32x4 wB0lo = *(const f32x4*)(wpA + 96);
    const f32x4 wB0hi = *(const f32x4*)(wpA + 100);
    const f32x4 wB1lo = *(const f32x4*)(wpB + 96);
    const f32x4 wB1hi = *(const f32x4*)(wpB + 100);

    f32x2 pA[4], pB[4];
#pragma unroll
    for (int dd = 0; dd < 4; ++dd) { pA[dd] = (f32x2){0.f, 0.f}; pB[dd] = (f32x2){0.f, 0.f}; }

    const float* cgp = cgall + (mpL * NP + pi) * 12;
    for (int i = i0; i <= i1; ++i) {
      const float cgv = cgp[i];
      int j = mK0l - i;
      j = j < 0 ? 0 : (j > n2 - 1 ? n2 - 1 : j);   // clamped; cg==0 when out-of-diag
      const float* x2p = x2base + (R2 + j) * 196;
      f32x2 xv[4];
      *(f32x4*)&xv[0] = *(const f32x4*)x2p;
      *(f32x4*)&xv[2] = *(const f32x4*)(x2p + 4);
      const float* x1p = x1base + (R1 + i) * 196;
      const float sA = cgv * x1p[0];
      const float sB = cgv * x1p[4];
      const f32x2 svA = {sA, sA}, svB = {sB, sB};
#pragma unroll
      for (int dd = 0; dd < 4; ++dd) {
        pA[dd] += svA * xv[dd];
        pB[dd] += svB * xv[dd];
      }
    }
    // pack A-fragments
    union { unsigned int u[4]; bf16x8 v; } zA, zB;
#pragma unroll
    for (int dd = 0; dd < 4; ++dd) {
      union { __hip_bfloat162 h2; unsigned int u; } z;
      z.h2 = __float22bfloat162_rn(make_float2(pA[dd].x, pA[dd].y)); zA.u[dd] = z.u;
      z.h2 = __float22bfloat162_rn(make_float2(pB[dd].x, pB[dd].y)); zB.u[dd] = z.u;
    }
    // convert W fragments and accumulate
    const bf16x8 wfA0 = cvt8(wA0lo, wA0hi);
    const bf16x8 wfA1 = cvt8(wA1lo, wA1hi);
    const bf16x8 wfB0 = cvt8(wB0lo, wB0hi);
    const bf16x8 wfB1 = cvt8(wB1lo, wB1hi);
    accC0 = __builtin_amdgcn_mfma_f32_16x16x32_bf16(zA.v, wfA0, accC0, 0, 0, 0);
    accC0 = __builtin_amdgcn_mfma_f32_16x16x32_bf16(zB.v, wfB0, accC0, 0, 0, 0);
    accC1 = __builtin_amdgcn_mfma_f32_16x16x32_bf16(zA.v, wfA1, accC1, 0, 0, 0);
    accC1 = __builtin_amdgcn_mfma_f32_16x16x32_bf16(zB.v, wfB1, accC1, 0, 0, 0);
  }

  // ---- cross-wave k-reduction over 9 waves ----
  {
    const int col16 = lane & 15;      // D: col = h (lo half), row = (lane>>4)*4+reg
    const int rbase = w * 16 + (lane >> 4) * 4;
#pragma unroll
    for (int r = 0; r < 4; ++r) {
      red[(rbase + r) * 32 + col16]      = accC0[r];
      red[(rbase + r) * 32 + 16 + col16] = accC1[r];
    }
  }
  __syncthreads();
  if (t < 512) {
    const int row = t >> 5, h = t & 31;   // 512: 16 rows x 32 h
    float v = 0.f;
#pragma unroll
    for (int ww = 0; ww < 9; ++ww) v += red[ww * 512 + row * 32 + h];
    const int ob = row & 7, omL = row >> 3;
    const int mp = mp0 + omL;
    if (mp <= 2 * L)
      P.out[(size_t)(b0 + ob) * 1152 + h * 36 + L * L + mp] = v;
  }
}

__global__ __launch_bounds__(576, 5)
void CGLayer_main(Params P) {
  const int mb = blockIdx.x;
  const int l = c_mb_l[mb], mp0 = c_mb_m0[mb];
  const int btile = blockIdx.y;
  switch (l) {
    case 0: body<0>(P, mp0, btile); break;
    case 1: body<1>(P, mp0, btile); break;
    case 2: body<2>(P, mp0, btile); break;
    case 3: body<3>(P, mp0, btile); break;
    case 4: body<4>(P, mp0, btile); break;
    default: body<5>(P, mp0, btile); break;
  }
}

extern "C" void kernel_launch(void* const* d_in, const int* in_sizes, int n_in,
                              void* d_out, int out_size, void* d_ws, size_t ws_size,
                              hipStream_t stream) {
  Params P;
  for (int i = 0; i < 6; ++i) P.x[i] = (const float*)d_in[i];
  for (int i = 0; i < 6; ++i) P.W[i] = (const float*)d_in[6 + i];
  P.cg  = (const float*)d_in[12];
  P.out = (float*)d_out;

  dim3 grid(21, 32);
  CGLayer_main<<<grid, 576, SMEM_FLOATS * sizeof(float), stream>>>(P);
}

// Round 6
// 149.030 us; speedup vs baseline: 1.6437x; 1.6437x over previous
//
#include <hip/hip_runtime.h>
#include <hip/hip_bf16.h>

typedef __attribute__((ext_vector_type(8))) short bf16x8;
typedef __attribute__((ext_vector_type(4))) float f32x4;
typedef __attribute__((ext_vector_type(2))) float f32x2;

struct Params {
  const float* x[6];
  const float* W[6];
  const float* cg;
  float* out;
  unsigned short* Wb;   // ws: W pre-swizzled to bf16 B-fragment order (4,091,904 B)
};

constexpr int NPAIRS_C[6] = {6, 15, 21, 24, 24, 21};
constexpr int POFF_C[6]   = {0, 6, 21, 42, 66, 90};
constexpr size_t WBASE_C[6] = {0, 110592, 387072, 774144, 1216512, 1658880};
constexpr int KL_C[6]   = {3456, 8640, 12096, 13824, 13824, 12096};
constexpr int LOFF_C[6] = {0, 1, 4, 9, 16, 25};   // row offset of l in xall
#define XSTRIDE 204       // % 32 == 12 -> adjacent rows shift 12 banks; 204*4B = 16B-aligned

constexpr int TL1[111] = {
  0,1,2,3,4,5,
  0,1,1,1,2,2,2,3,3,3,4,4,4,5,5,
  0,1,1,1,2,2,2,2,2,3,3,3,3,3,4,4,4,4,5,5,5,
  0,1,1,1,2,2,2,2,2,3,3,3,3,3,3,4,4,4,4,4,5,5,5,5,
  0,1,1,1,2,2,2,2,3,3,3,3,3,4,4,4,4,4,4,5,5,5,5,5,
  0,1,1,2,2,2,3,3,3,3,4,4,4,4,4,5,5,5,5,5,5
};
constexpr int TL2R[111] = {
  0,1,2,3,4,5,
  1,0,1,2,1,2,3,2,3,4,3,4,5,4,5,
  2,1,2,3,0,1,2,3,4,1,2,3,4,5,2,3,4,5,3,4,5,
  3,2,3,4,1,2,3,4,5,0,1,2,3,4,5,1,2,3,4,5,2,3,4,5,
  4,3,4,5,2,3,4,5,1,2,3,4,5,0,1,2,3,4,5,1,2,3,4,5,
  5,4,5,3,4,5,2,3,4,5,1,2,3,4,5,0,1,2,3,4,5
};

__constant__ int c_l1[111] = {
  0,1,2,3,4,5,
  0,1,1,1,2,2,2,3,3,3,4,4,4,5,5,
  0,1,1,1,2,2,2,2,2,3,3,3,3,3,4,4,4,4,5,5,5,
  0,1,1,1,2,2,2,2,2,3,3,3,3,3,3,4,4,4,4,4,5,5,5,5,
  0,1,1,1,2,2,2,2,3,3,3,3,3,4,4,4,4,4,4,5,5,5,5,5,
  0,1,1,2,2,2,3,3,3,3,4,4,4,4,4,5,5,5,5,5,5
};
__constant__ int c_l2[111] = {
  0,1,2,3,4,5,
  1,0,1,2,1,2,3,2,3,4,3,4,5,4,5,
  2,1,2,3,0,1,2,3,4,1,2,3,4,5,2,3,4,5,3,4,5,
  3,2,3,4,1,2,3,4,5,0,1,2,3,4,5,1,2,3,4,5,2,3,4,5,
  4,3,4,5,2,3,4,5,1,2,3,4,5,0,1,2,3,4,5,1,2,3,4,5,
  5,4,5,3,4,5,2,3,4,5,1,2,3,4,5,0,1,2,3,4,5
};
// 21 (L, mp0) blocks, heavy-L first; each block covers mp0, mp0+1
__constant__ int c_mb_l[21]  = {5,5,5,5,5,5, 4,4,4,4,4, 3,3,3,3, 2,2,2, 1,1, 0};
__constant__ int c_mb_m0[21] = {0,2,4,6,8,10, 0,2,4,6,8, 0,2,4,6, 0,2,4, 0,2, 0};
// 3-chunk groups: wave w owns chunks {GA3[w], GA3[w]+3, GA3[w]+6} — same d0, c += 4, 8
__constant__ int c_GA3[6] = {0,1,2,9,10,11};

// ---------- W swizzle: fp32 [h][k] -> bf16 B-fragment stream (verified R4) ----------
template<int L>
__device__ __forceinline__ void swz(const Params& P, int u8) {
  constexpr int KL = KL_C[L];
  constexpr int KL8 = KL / 8;
  if (u8 >= 32 * KL8) return;
  const int h  = u8 / KL8;
  const int k  = (u8 - h * KL8) * 8;
  const int pair = k / 576;
  const int kin  = k - pair * 576;
  const int kc = kin >> 5;
  const int g  = (kin >> 3) & 3;
  const float* src = P.W[L] + (size_t)h * KL + k;
  f32x4 v0 = *(const f32x4*)src;
  f32x4 v1 = *(const f32x4*)(src + 4);
  union { __hip_bfloat162 h2; unsigned int u; } z;
  unsigned int o0, o1, o2, o3;
  z.h2 = __float22bfloat162_rn(make_float2(v0.x, v0.y)); o0 = z.u;
  z.h2 = __float22bfloat162_rn(make_float2(v0.z, v0.w)); o1 = z.u;
  z.h2 = __float22bfloat162_rn(make_float2(v1.x, v1.y)); o2 = z.u;
  z.h2 = __float22bfloat162_rn(make_float2(v1.z, v1.w)); o3 = z.u;
  const size_t dst = WBASE_C[L] + (size_t)pair * 18432 + kc * 1024 + (h >> 4) * 512
                   + ((size_t)(g * 16 + (h & 15))) * 8;
  *(uint4*)(P.Wb + dst) = make_uint4(o0, o1, o2, o3);
}

__global__ __launch_bounds__(256)
void swizzle_W(Params P) {
  const int u8 = blockIdx.x * 256 + threadIdx.x;
  switch (blockIdx.y) {
    case 0: swz<0>(P, u8); break;
    case 1: swz<1>(P, u8); break;
    case 2: swz<2>(P, u8); break;
    case 3: swz<3>(P, u8); break;
    case 4: swz<4>(P, u8); break;
    default: swz<5>(P, u8); break;
  }
}

// ---------- LDS layout (float units) ----------
#define XALL_F 0          // [36 rows][XSTRIDE] f32 = 7344
#define CG_F   7344       // [2][NP][12] f32 <= 576
#define RED_F  7920       // [6][16][32] f32 = 3072
#define SMEM_FLOATS 10992 // 43,968 B -> 3 blocks/CU

template<int L>
__device__ __forceinline__ void body(const Params& P, const int mp0, const int btile) {
  constexpr int NP  = NPAIRS_C[L];
  constexpr int OFF = POFF_C[L];
  extern __shared__ float smem[];
  float* xall  = smem + XALL_F;
  float* cgall = smem + CG_F;
  float* red   = smem + RED_F;

  const int t    = threadIdx.x;          // 384 threads = 6 waves
  const int lane = t & 63;
  const int w    = t >> 6;               // wave = 3-chunk group id (0..5)
  const int q8   = lane >> 4;            // A-frag k-quad
  const int rI   = lane & 15;            // A-frag row: b = rI&7, mpL = rI>>3
  const int b    = rI & 7;
  const int mpL  = rI >> 3;
  const int b0   = btile * 8;

  // ---- stage all x, transposed, fp32 ----
#pragma unroll
  for (int l = 0; l < 6; ++l) {
    const int n = 2 * l + 1;
    const float* src = P.x[l] + (size_t)b0 * 24 * n;
    const int tot = 8 * 24 * n;
    for (int e = t; e < tot; e += 384) {
      const int bc = e / n;                  // compile-time divisor
      const int i  = e - bc * n;
      xall[(LOFF_C[l] + i) * XSTRIDE + bc] = src[e];
    }
  }
  // ---- stage cg diagonals for mp0 and mp0+1 (zeros where invalid) ----
  for (int e = t; e < 2 * NP * 12; e += 384) {
    const int i  = e % 12;
    const int r  = e / 12;
    const int pi = r % NP;
    const int mL = r / NP;
    const int l1 = c_l1[OFF + pi], l2 = c_l2[OFF + pi];
    const int mp = mp0 + mL;
    const int j  = mp + l1 + l2 - L - i;
    float v = 0.f;
    if (mp <= 2 * L && i <= 2 * l1 && j >= 0 && j <= 2 * l2)
      v = P.cg[((size_t)(((l1 * 6 + l2) * 6 + L) * 11 + mp) * 11 + i) * 11 + j];
    cgall[(mL * NP + pi) * 12 + i] = v;
  }
  __syncthreads();

  f32x4 accC0 = {0.f, 0.f, 0.f, 0.f};   // h 0..15
  f32x4 accC1 = {0.f, 0.f, 0.f, 0.f};   // h 16..31
  const int colb = b * 24;

  // this wave's 3-chunk group
  const int kcA = c_GA3[w];
  const int k0  = kcA * 32 + q8 * 8;
  const int cA  = k0 / 24;               // div by constant
  const int d0  = k0 - cA * 24;          // in {0,8,16}
  const float* x2base = xall + colb + d0;
  const float* x1base = xall + colb + cA;   // x1 for chunks B/C at +4/+8

#pragma unroll
  for (int pi = 0; pi < NP; ++pi) {
    const int l1 = TL1[OFF + pi], l2 = TL2R[OFF + pi];   // folded by unroll
    const int n1 = 2 * l1 + 1, n2 = 2 * l2 + 1;
    const int R1 = LOFF_C[l1], R2 = LOFF_C[l2];
    const int mK0w = mp0 + l1 + l2 - L;        // wave-uniform (mpL=0)
    const int mK0l = mK0w + mpL;               // per-lane
    const int i0 = (mK0w - (n2 - 1)) > 0 ? (mK0w - (n2 - 1)) : 0;
    const int i1 = (n1 - 1) < (mK0w + 1) ? (n1 - 1) : (mK0w + 1);

    // prefetch bf16 B-fragments (L2-resident Wb); latency hides under diag loop
    const unsigned short* wbp = P.Wb + WBASE_C[L] + (size_t)pi * 18432 + lane * 8;
    const bf16x8 wfA0 = *(const bf16x8*)(wbp + kcA * 1024);
    const bf16x8 wfA1 = *(const bf16x8*)(wbp + kcA * 1024 + 512);
    const bf16x8 wfB0 = *(const bf16x8*)(wbp + (kcA + 3) * 1024);
    const bf16x8 wfB1 = *(const bf16x8*)(wbp + (kcA + 3) * 1024 + 512);
    const bf16x8 wfC0 = *(const bf16x8*)(wbp + (kcA + 6) * 1024);
    const bf16x8 wfC1 = *(const bf16x8*)(wbp + (kcA + 6) * 1024 + 512);

    f32x2 pA[4], pB[4], pC[4];
#pragma unroll
    for (int dd = 0; dd < 4; ++dd) {
      pA[dd] = (f32x2){0.f, 0.f};
      pB[dd] = (f32x2){0.f, 0.f};
      pC[dd] = (f32x2){0.f, 0.f};
    }

    const float* cgp = cgall + (mpL * NP + pi) * 12;
    for (int i = i0; i <= i1; ++i) {
      const float cgv = cgp[i];
      int j = mK0l - i;
      j = j < 0 ? 0 : (j > n2 - 1 ? n2 - 1 : j);   // clamped; cg==0 when out-of-diag
      const float* x2p = x2base + (R2 + j) * XSTRIDE;
      f32x2 xv[4];
      *(f32x4*)&xv[0] = *(const f32x4*)x2p;
      *(f32x4*)&xv[2] = *(const f32x4*)(x2p + 4);
      const float* x1p = x1base + (R1 + i) * XSTRIDE;
      const float sA = cgv * x1p[0];
      const float sB = cgv * x1p[4];
      const float sC = cgv * x1p[8];
      const f32x2 svA = {sA, sA}, svB = {sB, sB}, svC = {sC, sC};
#pragma unroll
      for (int dd = 0; dd < 4; ++dd) {
        pA[dd] += svA * xv[dd];
        pB[dd] += svB * xv[dd];
        pC[dd] += svC * xv[dd];
      }
    }
    // pack A-fragments
    union { unsigned int u[4]; bf16x8 v; } zA, zB, zC;
#pragma unroll
    for (int dd = 0; dd < 4; ++dd) {
      union { __hip_bfloat162 h2; unsigned int u; } z;
      z.h2 = __float22bfloat162_rn(make_float2(pA[dd].x, pA[dd].y)); zA.u[dd] = z.u;
      z.h2 = __float22bfloat162_rn(make_float2(pB[dd].x, pB[dd].y)); zB.u[dd] = z.u;
      z.h2 = __float22bfloat162_rn(make_float2(pC[dd].x, pC[dd].y)); zC.u[dd] = z.u;
    }
    accC0 = __builtin_amdgcn_mfma_f32_16x16x32_bf16(zA.v, wfA0, accC0, 0, 0, 0);
    accC0 = __builtin_amdgcn_mfma_f32_16x16x32_bf16(zB.v, wfB0, accC0, 0, 0, 0);
    accC0 = __builtin_amdgcn_mfma_f32_16x16x32_bf16(zC.v, wfC0, accC0, 0, 0, 0);
    accC1 = __builtin_amdgcn_mfma_f32_16x16x32_bf16(zA.v, wfA1, accC1, 0, 0, 0);
    accC1 = __builtin_amdgcn_mfma_f32_16x16x32_bf16(zB.v, wfB1, accC1, 0, 0, 0);
    accC1 = __builtin_amdgcn_mfma_f32_16x16x32_bf16(zC.v, wfC1, accC1, 0, 0, 0);
  }

  // ---- cross-wave k-reduction over 6 waves ----
  {
    const int col16 = lane & 15;      // D: col = h (lo half), row = (lane>>4)*4+reg
    const int rbase = w * 16 + (lane >> 4) * 4;
#pragma unroll
    for (int r = 0; r < 4; ++r) {
      red[(rbase + r) * 32 + col16]      = accC0[r];
      red[(rbase + r) * 32 + 16 + col16] = accC1[r];
    }
  }
  __syncthreads();
  for (int idx = t; idx < 512; idx += 384) {
    const int row = idx >> 5, h = idx & 31;   // 512: 16 rows x 32 h
    float v = 0.f;
#pragma unroll
    for (int ww = 0; ww < 6; ++ww) v += red[ww * 512 + row * 32 + h];
    const int ob = row & 7, omL = row >> 3;
    const int mp = mp0 + omL;
    if (mp <= 2 * L)
      P.out[(size_t)(b0 + ob) * 1152 + h * 36 + L * L + mp] = v;
  }
}

__global__ __launch_bounds__(384, 5)
void CGLayer_main(Params P) {
  const int mb = blockIdx.x;
  const int l = c_mb_l[mb], mp0 = c_mb_m0[mb];
  const int btile = blockIdx.y;
  switch (l) {
    case 0: body<0>(P, mp0, btile); break;
    case 1: body<1>(P, mp0, btile); break;
    case 2: body<2>(P, mp0, btile); break;
    case 3: body<3>(P, mp0, btile); break;
    case 4: body<4>(P, mp0, btile); break;
    default: body<5>(P, mp0, btile); break;
  }
}

extern "C" void kernel_launch(void* const* d_in, const int* in_sizes, int n_in,
                              void* d_out, int out_size, void* d_ws, size_t ws_size,
                              hipStream_t stream) {
  Params P;
  for (int i = 0; i < 6; ++i) P.x[i] = (const float*)d_in[i];
  for (int i = 0; i < 6; ++i) P.W[i] = (const float*)d_in[6 + i];
  P.cg  = (const float*)d_in[12];
  P.out = (float*)d_out;
  P.Wb  = (unsigned short*)d_ws;   // needs 4,091,904 bytes

  dim3 sg(216, 6);
  swizzle_W<<<sg, 256, 0, stream>>>(P);
  dim3 grid(21, 32);
  CGLayer_main<<<grid, 384, SMEM_FLOATS * sizeof(float), stream>>>(P);
}